// Round 12
// baseline (614.187 us; speedup 1.0000x reference)
//
#include <hip/hip_runtime.h>
#include <hip/hip_bf16.h>

typedef __bf16 bf16_t;
typedef _Float16 fp16_t;
typedef _Float16 f16x8 __attribute__((ext_vector_type(8)));
typedef _Float16 f16x4 __attribute__((ext_vector_type(4)));
typedef __bf16 bf16x4 __attribute__((ext_vector_type(4)));
typedef float f32x4 __attribute__((ext_vector_type(4)));

#define ATTN_SCALE 0.17677669529663687f  // 1/sqrt(32)
#define K_SHIFT 64.0f                    // k logits ~N(0,16), max ~88
#define Q_SHIFT 8.0f                     // q*scale logits ~N(0,2.83)

__device__ __forceinline__ void gload16(const void* g, void* l) {
  __builtin_amdgcn_global_load_lds((const __attribute__((address_space(1))) void*)g,
                                   (__attribute__((address_space(3))) void*)l, 16, 0, 0);
}

// ---------------- prep: pack w_qkv into MFMA-fragment-major fp16 table --------------------
// Bpack[nt(12)][kk(8)][f(4)][l(64)][8]: B[n][k] = w_qkv[k][n]; n = nt*64+f*16+(l&15),
// k = kk*32+(l>>4)*8+e. A wave's fragment load = 64 lanes x 16B contiguous = 1KB.
__global__ __launch_bounds__(256) void prep_pack(
    const float* __restrict__ w_qkv, fp16_t* __restrict__ Bpack) {
  int idx = blockIdx.x * 256 + threadIdx.x;  // 24576 groups
  int l = idx & 63;
  int rest = idx >> 6;
  int f = rest & 3;
  int kk = (rest >> 2) & 7;
  int nt = rest >> 5;
  int n = nt * 64 + f * 16 + (l & 15);
  int k0 = kk * 32 + (l >> 4) * 8;
  f16x8 v;
#pragma unroll
  for (int e = 0; e < 8; ++e) v[e] = (fp16_t)w_qkv[(k0 + e) * 768 + n];
  ((f16x8*)Bpack)[idx] = v;
}

// ---------------- fused qvk + ctx (R8 structure, 48.5 KB LDS -> 3 blocks/CU) --------------
// Block = 64 rows. Stage xn fp16 -> LDS. Phase q: unit GEMMs -> e=exp(q*s-8) fp16.
// Phases 0,1 (4 heads each): k,v units -> acc; 2 sub-phases stream 32-row P/V chunks
// through padded [32][132] LDS tiles; VALU ctx accumulates S/Z across chunks.
__global__ __launch_bounds__(256, 3) void gemm_qvk_ctx(
    const float* __restrict__ x, const float* __restrict__ gamma_in,
    const fp16_t* __restrict__ Bpack, const float* __restrict__ bias,
    fp16_t* __restrict__ qe_out, float* __restrict__ part) {
  __shared__ fp16_t A[64 * 256];   // 32 KB xn panel
  __shared__ bf16_t Pl[32 * 132];  // 8.25 KB p chunk (32 rows x 128 d-cols, +4 pad)
  __shared__ fp16_t Vl[32 * 132];  // 8.25 KB v chunk
  int t = threadIdx.x, l = t & 63, w = t >> 6;
  int lr = l >> 4, lc = l & 15;
  int bx = blockIdx.x;
  int m0 = bx * 64;

#pragma unroll
  for (int i = 0; i < 8; ++i) {  // stage xn = x*(gamma+1)*16 -> fp16, slot-XOR swizzle
    int idx = i * 256 + t;
    int r = idx >> 5, c8 = idx & 31;
    const float* src = x + (size_t)(m0 + r) * 256 + c8 * 8;
    const float* gsc = gamma_in + c8 * 8;
    f16x8 hv;
#pragma unroll
    for (int j = 0; j < 8; ++j) hv[j] = (fp16_t)(src[j] * (gsc[j] + 1.f) * 16.f);
    *(f16x8*)&A[r * 256 + ((c8 ^ (r & 31)) * 8)] = hv;
  }
  __syncthreads();

  // 64x64x256 unit GEMM from LDS A + packed-B (L2)
  auto run_unit = [&](int nt, f32x4 acc[4][4]) {
    const fp16_t* Bp = Bpack + (size_t)nt * 16384;
#pragma unroll
    for (int mf = 0; mf < 4; ++mf)
#pragma unroll
      for (int nf = 0; nf < 4; ++nf) acc[mf][nf] = (f32x4){0.f, 0.f, 0.f, 0.f};
#pragma unroll
    for (int kk = 0; kk < 8; ++kk) {
      f16x8 af[4], bfr[4];
#pragma unroll
      for (int f = 0; f < 4; ++f) {
        int ra = f * 16 + lc;
        af[f] = *(const f16x8*)&A[ra * 256 + (((kk * 4 + lr) ^ (ra & 31)) * 8)];
        bfr[f] = *(const f16x8*)(Bp + (size_t)(kk * 4 + f) * 512 + l * 8);
      }
#pragma unroll
      for (int mf = 0; mf < 4; ++mf)
#pragma unroll
        for (int nf = 0; nf < 4; ++nf)
          acc[mf][nf] = __builtin_amdgcn_mfma_f32_16x16x32_f16(af[mf], bfr[nf], acc[mf][nf], 0, 0, 0);
    }
  };

  {  // phase q: nt = w; e = fp16(exp(q*scale - 8)) -> global (row-major)
    f32x4 acc[4][4];
    run_unit(w, acc);
    int n0 = w * 64;
    float bq[4];
#pragma unroll
    for (int nf = 0; nf < 4; ++nf) bq[nf] = bias[n0 + nf * 16 + lc];
#pragma unroll
    for (int mf = 0; mf < 4; ++mf)
#pragma unroll
      for (int r = 0; r < 4; ++r) {
        int row = m0 + mf * 16 + lr * 4 + r;
#pragma unroll
        for (int nf = 0; nf < 4; ++nf) {
          float ql = (acc[mf][nf][r] + bq[nf]) * ATTN_SCALE;
          qe_out[(size_t)row * 256 + n0 + nf * 16 + lc] = (fp16_t)__expf(ql - Q_SHIFT);
        }
      }
  }

  // phases 0,1: k,v units -> 2x 32-row P/V chunks -> VALU ctx
  int hq = t >> 6, s = t & 63;          // ctx role: head-in-phase, subthread
  int d0 = (s >> 3) * 4, e0 = (s & 7) * 4;
  bool isK = (w < 2);
  int wu = w & 1;                        // unit-within-half
  for (int ph = 0; ph < 2; ++ph) {
    f32x4 acc[4][4];
    int nt = (isK ? 4 : 8) + ph * 2 + wu;
    run_unit(nt, acc);
    int n0 = nt * 64;                    // global qkv col base (bias index)
    int lcb = wu * 64;                   // local col base within 128-col half
    float bv[4];
#pragma unroll
    for (int nf = 0; nf < 4; ++nf) bv[nf] = bias[n0 + nf * 16 + lc];

    float S[4][4] = {};
    float z[4] = {0.f, 0.f, 0.f, 0.f};
    int hb = hq * 32;
#pragma unroll
    for (int c = 0; c < 2; ++c) {  // 32-row chunks: acc mf {2c, 2c+1}
#pragma unroll
      for (int m = 0; m < 2; ++m)
#pragma unroll
        for (int r = 0; r < 4; ++r) {
          int rl = m * 16 + lr * 4 + r;  // local row 0..31
          int mf = c * 2 + m;
#pragma unroll
          for (int nf = 0; nf < 4; ++nf) {
            float val = acc[mf][nf][r] + bv[nf];
            if (isK) Pl[rl * 132 + lcb + nf * 16 + lc] = (bf16_t)__expf(val - K_SHIFT);
            else     Vl[rl * 132 + lcb + nf * 16 + lc] = (fp16_t)val;
          }
        }
      __syncthreads();  // chunk's P/V complete
      for (int r = 0; r < 32; ++r) {
        bf16x4 pd4 = *(const bf16x4*)&Pl[r * 132 + hb + d0];
        f16x4 vv4 = *(const f16x4*)&Vl[r * 132 + hb + e0];
        float pd[4] = {(float)pd4[0], (float)pd4[1], (float)pd4[2], (float)pd4[3]};
        float vv[4] = {(float)vv4[0], (float)vv4[1], (float)vv4[2], (float)vv4[3]};
#pragma unroll
        for (int i = 0; i < 4; ++i) {
#pragma unroll
          for (int j = 0; j < 4; ++j) S[i][j] += pd[i] * vv[j];
          z[i] += pd[i];
        }
      }
      __syncthreads();  // ctx reads done before next chunk/phase overwrites Pl/Vl
    }
    float* pp = part + (size_t)bx * 8448 + (ph * 4 + hq) * 1056;
#pragma unroll
    for (int i = 0; i < 4; ++i)
      *(float4*)&pp[(d0 + i) * 32 + e0] = (float4){S[i][0], S[i][1], S[i][2], S[i][3]};
    if (e0 == 0) {
#pragma unroll
      for (int i = 0; i < 4; ++i) pp[1024 + d0 + i] = z[i];
    }
  }
}

// ---------------- fold partials + mem_kv into packed per-batch y-weight table -------------
__global__ __launch_bounds__(256) void build_wt(
    const float* __restrict__ part, const float* __restrict__ w_out,
    const float* __restrict__ mem_kv, fp16_t* __restrict__ Bpacky) {
  int bh = blockIdx.x;  // 0..127
  int b = bh >> 3, h = bh & 7;
  int t = threadIdx.x;
  __shared__ float S[32][32];
  __shared__ float Zr[32];
  __shared__ float W[32][256];
  for (int idx = t; idx < 1024; idx += 256) {
    float s = 0.f;
    for (int c = 0; c < 64; ++c) s += part[((size_t)(b * 64 + c)) * 8448 + h * 1056 + idx];
    S[idx >> 5][idx & 31] = s;
  }
  if (t < 32) {
    float zz = 0.f;
    for (int c = 0; c < 64; ++c) zz += part[((size_t)(b * 64 + c)) * 8448 + h * 1056 + 1024 + t];
    Zr[t] = zz;
  }
  for (int i = t; i < 32 * 256; i += 256) W[i >> 8][i & 255] = w_out[(h * 32 + (i >> 8)) * 256 + (i & 255)];
  __syncthreads();
  if (t < 32) {  // fold 4 memory-kv rows (same fixed shift as k)
    int dd = t;
    for (int m = 0; m < 4; ++m) {
      float p = __expf(mem_kv[h * 128 + m * 32 + dd] - K_SHIFT);
      Zr[dd] += p;
      for (int e = 0; e < 32; ++e) S[dd][e] += p * mem_kv[1024 + h * 128 + m * 32 + e];
    }
  }
  __syncthreads();
  int c = t;
  int nt = c >> 6, f = (c >> 4) & 3, lc = c & 15;
  for (int dd = 0; dd < 32; ++dd) {
    float acc = 0;
#pragma unroll 8
    for (int e = 0; e < 32; ++e) acc += S[dd][e] * W[e][c];
    int kcol = h * 32 + dd;
    int kk = kcol >> 5, lr = (kcol & 31) >> 3, e8 = kcol & 7;
    size_t addr = ((((size_t)(b * 4 + nt) * 8 + kk) * 4 + f) * 64 + (lr * 16 + lc)) * 8 + e8;
    Bpacky[addr] = (fp16_t)(acc / Zr[dd]);
  }
}

// ---------------- y GEMM: e-panel staged, per-(row,head) normalize in LDS, packed wt ------
__global__ __launch_bounds__(256) void gemm_y(
    const fp16_t* __restrict__ qe, const fp16_t* __restrict__ Bpacky,
    const float* __restrict__ b_out, const float* __restrict__ gamma_out,
    float* __restrict__ y_out) {
  __shared__ fp16_t A[64 * 256];  // 32 KB
  __shared__ float zbuf[64][8];   // rcpZ per (row, head)
  int t = threadIdx.x, l = t & 63, w = t >> 6;
  int lr = l >> 4, lc = l & 15;
  int m0 = blockIdx.x * 64;
#pragma unroll
  for (int i = 0; i < 8; ++i) {  // linear LDS dest, inverse-swizzled global source (G21)
    int idx = i * 256 + t;
    int r = idx >> 5, cs = idx & 31;
    gload16(qe + (size_t)(m0 + r) * 256 + ((cs ^ (r & 31)) * 8), &A[idx * 8]);
  }
  __syncthreads();

#pragma unroll
  for (int pi = 0; pi < 2; ++pi) {  // Z per (row, head): 512 pairs / 256 threads
    int p = pi * 256 + t;
    int r = p >> 3, hh = p & 7;
    float zs = 0.f;
#pragma unroll
    for (int c = 0; c < 4; ++c) {
      int cs = (hh * 4 + c) ^ (r & 31);
      f16x8 vv = *(const f16x8*)&A[r * 256 + cs * 8];
#pragma unroll
      for (int j = 0; j < 8; ++j) zs += (float)vv[j];
    }
    zbuf[r][hh] = 1.f / zs;
  }
  __syncthreads();

#pragma unroll
  for (int i = 0; i < 8; ++i) {  // rescale own staged slots: qs = e * rcpZ
    int idx = i * 256 + t;
    int r = idx >> 5, cs = idx & 31;
    int hh = (cs ^ (r & 31)) >> 2;
    float sc = zbuf[r][hh];
    f16x8 vv = *(const f16x8*)&A[idx * 8];
#pragma unroll
    for (int j = 0; j < 8; ++j) vv[j] = (fp16_t)((float)vv[j] * sc);
    *(f16x8*)&A[idx * 8] = vv;
  }
  __syncthreads();

  int n0 = w * 64;
  const fp16_t* Bp = Bpacky + (size_t)(m0 >> 12) * 65536 + (size_t)w * 16384;
  f32x4 acc[4][4];
#pragma unroll
  for (int mf = 0; mf < 4; ++mf)
#pragma unroll
    for (int nf = 0; nf < 4; ++nf) acc[mf][nf] = (f32x4){0.f, 0.f, 0.f, 0.f};
#pragma unroll
  for (int kk = 0; kk < 8; ++kk) {
    f16x8 af[4], bfr[4];
#pragma unroll
    for (int f = 0; f < 4; ++f) {
      int ra = f * 16 + lc;
      af[f] = *(const f16x8*)&A[ra * 256 + (((kk * 4 + lr) ^ (ra & 31)) * 8)];
      bfr[f] = *(const f16x8*)(Bp + (size_t)(kk * 4 + f) * 512 + l * 8);
    }
#pragma unroll
    for (int mf = 0; mf < 4; ++mf)
#pragma unroll
      for (int nf = 0; nf < 4; ++nf)
        acc[mf][nf] = __builtin_amdgcn_mfma_f32_16x16x32_f16(af[mf], bfr[nf], acc[mf][nf], 0, 0, 0);
  }
  float bv[4], gv[4];
#pragma unroll
  for (int nf = 0; nf < 4; ++nf) {
    int c = n0 + nf * 16 + lc;
    bv[nf] = b_out[c];
    gv[nf] = (gamma_out[c] + 1.f) * 16.f;
  }
#pragma unroll
  for (int mf = 0; mf < 4; ++mf)
#pragma unroll
    for (int r = 0; r < 4; ++r) {
      int row = m0 + mf * 16 + lr * 4 + r;
#pragma unroll
      for (int nf = 0; nf < 4; ++nf)
        y_out[(size_t)row * 256 + n0 + nf * 16 + lc] = (acc[mf][nf][r] + bv[nf]) * gv[nf];
    }
}

extern "C" void kernel_launch(void* const* d_in, const int* in_sizes, int n_in,
                              void* d_out, int out_size, void* d_ws, size_t ws_size,
                              hipStream_t stream) {
  const float* x        = (const float*)d_in[0];
  const float* gamma_in = (const float*)d_in[1];
  const float* w_qkv    = (const float*)d_in[2];
  const float* b_qkv    = (const float*)d_in[3];
  const float* mem_kv   = (const float*)d_in[4];
  const float* w_out    = (const float*)d_in[5];
  const float* b_out    = (const float*)d_in[6];
  const float* gamma_out= (const float*)d_in[7];
  float* y = (float*)d_out;

  char* ws = (char*)d_ws;
  fp16_t* qe     = (fp16_t*)(ws);                 // 32 MB    e = exp(q*scale-8), fp16
  fp16_t* Bpack  = (fp16_t*)(ws + 33554432);      // 384 KB   packed w_qkv frags
  fp16_t* Bpacky = (fp16_t*)(ws + 33947648);      // 2 MB     packed per-batch wt frags
  float*  part   = (float*)(ws + 36044800);       // 34.6 MB  S/Z partials (end ~71 MB)

  prep_pack<<<96, 256, 0, stream>>>(w_qkv, Bpack);
  gemm_qvk_ctx<<<1024, 256, 0, stream>>>(x, gamma_in, Bpack, b_qkv, qe, part);
  build_wt<<<128, 256, 0, stream>>>(part, w_out, mem_kv, Bpacky);
  gemm_y<<<1024, 256, 0, stream>>>(qe, Bpacky, b_out, gamma_out, y);
}

// Round 13
// 125.000 us; speedup vs baseline: 4.9135x; 4.9135x over previous
//
#include <hip/hip_runtime.h>
#include <hip/hip_bf16.h>

typedef __bf16 bf16_t;
typedef _Float16 fp16_t;
typedef _Float16 f16x8 __attribute__((ext_vector_type(8)));
typedef __bf16 bf16x8 __attribute__((ext_vector_type(8)));
typedef float f32x4 __attribute__((ext_vector_type(4)));

#define ATTN_SCALE 0.17677669529663687f  // 1/sqrt(32)
#define K_SHIFT 64.0f                    // k logits ~N(0,16), max ~88
#define Q_SHIFT 8.0f                     // q*scale logits ~N(0,2.83)

__device__ __forceinline__ void gload16(const void* g, void* l) {
  __builtin_amdgcn_global_load_lds((const __attribute__((address_space(1))) void*)g,
                                   (__attribute__((address_space(3))) void*)l, 16, 0, 0);
}

// ---------------- prep: pack w_qkv into MFMA-fragment-major fp16 table --------------------
// Bpack[nt(12)][kk(8)][f(4)][l(64)][8]: B[n][k] = w_qkv[k][n]; n = nt*64+f*16+(l&15),
// k = kk*32+(l>>4)*8+e. A wave's fragment load = 64 lanes x 16B contiguous = 1KB.
__global__ __launch_bounds__(256) void prep_pack(
    const float* __restrict__ w_qkv, fp16_t* __restrict__ Bpack) {
  int idx = blockIdx.x * 256 + threadIdx.x;  // 24576 groups
  int l = idx & 63;
  int rest = idx >> 6;
  int f = rest & 3;
  int kk = (rest >> 2) & 7;
  int nt = rest >> 5;
  int n = nt * 64 + f * 16 + (l & 15);
  int k0 = kk * 32 + (l >> 4) * 8;
  f16x8 v;
#pragma unroll
  for (int e = 0; e < 8; ++e) v[e] = (fp16_t)w_qkv[(k0 + e) * 768 + n];
  ((f16x8*)Bpack)[idx] = v;
}

// ---------------- fused qvk + MFMA-ctx (R8 skeleton; ctx moved to matrix pipe) ------------
// Block = 64 rows. Stage xn fp16 -> LDS. Phase q: unit GEMMs -> e=exp(q*s-8) fp16.
// Phases 0,1 (4 heads each): k,v units -> TRANSPOSED P^T[d][row], V^T[e][row] bf16 tiles
// in XOR-swizzled LDS -> per-head S = P^T x V via 16x16x32 bf16 MFMA; Z via B=ones.
__global__ __launch_bounds__(256) void gemm_qvk_ctx(
    const float* __restrict__ x, const float* __restrict__ gamma_in,
    const fp16_t* __restrict__ Bpack, const float* __restrict__ bias,
    fp16_t* __restrict__ qe_out, float* __restrict__ part) {
  __shared__ fp16_t A[64 * 256];   // 32 KB xn panel
  __shared__ bf16_t Pl[128 * 64];  // 16 KB P^T (128 d-cols x 64 rows, XOR-swizzled)
  __shared__ bf16_t Vl[128 * 64];  // 16 KB V^T              (total LDS = 64 KB exactly)
  int t = threadIdx.x, l = t & 63, w = t >> 6;
  int lr = l >> 4, lc = l & 15;
  int bx = blockIdx.x;
  int m0 = bx * 64;

#pragma unroll
  for (int i = 0; i < 8; ++i) {  // stage xn = x*(gamma+1)*16 -> fp16, slot-XOR swizzle
    int idx = i * 256 + t;
    int r = idx >> 5, c8 = idx & 31;
    const float* src = x + (size_t)(m0 + r) * 256 + c8 * 8;
    const float* gsc = gamma_in + c8 * 8;
    f16x8 hv;
#pragma unroll
    for (int j = 0; j < 8; ++j) hv[j] = (fp16_t)(src[j] * (gsc[j] + 1.f) * 16.f);
    *(f16x8*)&A[r * 256 + ((c8 ^ (r & 31)) * 8)] = hv;
  }
  __syncthreads();

  // 64x64x256 unit GEMM from LDS A + packed-B (L2)  [identical to R8]
  auto run_unit = [&](int nt, f32x4 acc[4][4]) {
    const fp16_t* Bp = Bpack + (size_t)nt * 16384;
#pragma unroll
    for (int mf = 0; mf < 4; ++mf)
#pragma unroll
      for (int nf = 0; nf < 4; ++nf) acc[mf][nf] = (f32x4){0.f, 0.f, 0.f, 0.f};
#pragma unroll
    for (int kk = 0; kk < 8; ++kk) {
      f16x8 af[4], bfr[4];
#pragma unroll
      for (int f = 0; f < 4; ++f) {
        int ra = f * 16 + lc;
        af[f] = *(const f16x8*)&A[ra * 256 + (((kk * 4 + lr) ^ (ra & 31)) * 8)];
        bfr[f] = *(const f16x8*)(Bp + (size_t)(kk * 4 + f) * 512 + l * 8);
      }
#pragma unroll
      for (int mf = 0; mf < 4; ++mf)
#pragma unroll
        for (int nf = 0; nf < 4; ++nf)
          acc[mf][nf] = __builtin_amdgcn_mfma_f32_16x16x32_f16(af[mf], bfr[nf], acc[mf][nf], 0, 0, 0);
    }
  };

  {  // phase q: nt = w; e = fp16(exp(q*scale - 8)) -> global (row-major)
    f32x4 acc[4][4];
    run_unit(w, acc);
    int n0 = w * 64;
    float bq[4];
#pragma unroll
    for (int nf = 0; nf < 4; ++nf) bq[nf] = bias[n0 + nf * 16 + lc];
#pragma unroll
    for (int mf = 0; mf < 4; ++mf)
#pragma unroll
      for (int r = 0; r < 4; ++r) {
        int row = m0 + mf * 16 + lr * 4 + r;
#pragma unroll
        for (int nf = 0; nf < 4; ++nf) {
          float ql = (acc[mf][nf][r] + bq[nf]) * ATTN_SCALE;
          qe_out[(size_t)row * 256 + n0 + nf * 16 + lc] = (fp16_t)__expf(ql - Q_SHIFT);
        }
      }
  }

  // phases 0,1: k,v units -> transposed LDS tiles -> MFMA ctx
  bool isK = (w < 2);
  int wu = w & 1;  // unit-within-half
  for (int ph = 0; ph < 2; ++ph) {
    f32x4 acc[4][4];
    int nt = (isK ? 4 : 8) + ph * 2 + wu;
    run_unit(nt, acc);
    int n0 = nt * 64;
    float bv[4];
#pragma unroll
    for (int nf = 0; nf < 4; ++nf) bv[nf] = bias[n0 + nf * 16 + lc];
#pragma unroll
    for (int mf = 0; mf < 4; ++mf)
#pragma unroll
      for (int r = 0; r < 4; ++r) {
        int row = mf * 16 + lr * 4 + r;  // local row 0..63
#pragma unroll
        for (int nf = 0; nf < 4; ++nf) {
          float val = acc[mf][nf][r] + bv[nf];
          int col = wu * 64 + nf * 16 + lc;  // local d/e col 0..127
          int addr = col * 64 + ((((row >> 3) ^ (col & 7)) << 3) | (row & 7));
          if (isK) Pl[addr] = (bf16_t)__expf(val - K_SHIFT);
          else     Vl[addr] = (bf16_t)val;
        }
      }
    __syncthreads();  // P^T/V^T complete

    {  // ctx via MFMA: wave = head; S = P^T x V (K=64 rows), Z via B=ones
      int hb = w * 32;
      f32x4 sacc[2][2];
      f32x4 zacc[2];
#pragma unroll
      for (int mf = 0; mf < 2; ++mf) {
#pragma unroll
        for (int nf = 0; nf < 2; ++nf) sacc[mf][nf] = (f32x4){0.f, 0.f, 0.f, 0.f};
        zacc[mf] = (f32x4){0.f, 0.f, 0.f, 0.f};
      }
      bf16x8 ones;
#pragma unroll
      for (int i = 0; i < 8; ++i) ones[i] = (bf16_t)1.0f;
#pragma unroll
      for (int kk = 0; kk < 2; ++kk) {
        bf16x8 ap[2], bvv[2];
#pragma unroll
        for (int mf = 0; mf < 2; ++mf) {
          int colA = hb + mf * 16 + lc;
          ap[mf] = *(const bf16x8*)&Pl[colA * 64 + (((kk * 4 + lr) ^ (colA & 7)) << 3)];
          bvv[mf] = *(const bf16x8*)&Vl[colA * 64 + (((kk * 4 + lr) ^ (colA & 7)) << 3)];
        }
#pragma unroll
        for (int mf = 0; mf < 2; ++mf) {
#pragma unroll
          for (int nf = 0; nf < 2; ++nf)
            sacc[mf][nf] = __builtin_amdgcn_mfma_f32_16x16x32_bf16(ap[mf], bvv[nf], sacc[mf][nf], 0, 0, 0);
          zacc[mf] = __builtin_amdgcn_mfma_f32_16x16x32_bf16(ap[mf], ones, zacc[mf], 0, 0, 0);
        }
      }
      float* pp = part + (size_t)bx * 8448 + (ph * 4 + w) * 1056;
#pragma unroll
      for (int mf = 0; mf < 2; ++mf)
#pragma unroll
        for (int r = 0; r < 4; ++r) {
          int dd = mf * 16 + lr * 4 + r;
#pragma unroll
          for (int nf = 0; nf < 2; ++nf) pp[dd * 32 + nf * 16 + lc] = sacc[mf][nf][r];
          if (lc == 0) pp[1024 + dd] = zacc[mf][r];
        }
    }
    __syncthreads();  // ctx reads done before next phase overwrites Pl/Vl
  }
}

// ---------------- fold partials + mem_kv into packed per-batch y-weight table -------------
__global__ __launch_bounds__(256) void build_wt(
    const float* __restrict__ part, const float* __restrict__ w_out,
    const float* __restrict__ mem_kv, fp16_t* __restrict__ Bpacky) {
  int bh = blockIdx.x;  // 0..127
  int b = bh >> 3, h = bh & 7;
  int t = threadIdx.x;
  __shared__ float S[32][32];
  __shared__ float Zr[32];
  __shared__ float W[32][256];
  for (int idx = t; idx < 1024; idx += 256) {
    float s = 0.f;
    for (int c = 0; c < 64; ++c) s += part[((size_t)(b * 64 + c)) * 8448 + h * 1056 + idx];
    S[idx >> 5][idx & 31] = s;
  }
  if (t < 32) {
    float zz = 0.f;
    for (int c = 0; c < 64; ++c) zz += part[((size_t)(b * 64 + c)) * 8448 + h * 1056 + 1024 + t];
    Zr[t] = zz;
  }
  for (int i = t; i < 32 * 256; i += 256) W[i >> 8][i & 255] = w_out[(h * 32 + (i >> 8)) * 256 + (i & 255)];
  __syncthreads();
  if (t < 32) {  // fold 4 memory-kv rows (same fixed shift as k)
    int dd = t;
    for (int m = 0; m < 4; ++m) {
      float p = __expf(mem_kv[h * 128 + m * 32 + dd] - K_SHIFT);
      Zr[dd] += p;
      for (int e = 0; e < 32; ++e) S[dd][e] += p * mem_kv[1024 + h * 128 + m * 32 + e];
    }
  }
  __syncthreads();
  int c = t;
  int nt = c >> 6, f = (c >> 4) & 3, lc = c & 15;
  for (int dd = 0; dd < 32; ++dd) {
    float acc = 0;
#pragma unroll 8
    for (int e = 0; e < 32; ++e) acc += S[dd][e] * W[e][c];
    int kcol = h * 32 + dd;
    int kk = kcol >> 5, lr = (kcol & 31) >> 3, e8 = kcol & 7;
    size_t addr = ((((size_t)(b * 4 + nt) * 8 + kk) * 4 + f) * 64 + (lr * 16 + lc)) * 8 + e8;
    Bpacky[addr] = (fp16_t)(acc / Zr[dd]);
  }
}

// ---------------- y GEMM: e-panel staged, per-(row,head) normalize in LDS, packed wt ------
__global__ __launch_bounds__(256) void gemm_y(
    const fp16_t* __restrict__ qe, const fp16_t* __restrict__ Bpacky,
    const float* __restrict__ b_out, const float* __restrict__ gamma_out,
    float* __restrict__ y_out) {
  __shared__ fp16_t A[64 * 256];  // 32 KB
  __shared__ float zbuf[64][8];   // rcpZ per (row, head)
  int t = threadIdx.x, l = t & 63, w = t >> 6;
  int lr = l >> 4, lc = l & 15;
  int m0 = blockIdx.x * 64;
#pragma unroll
  for (int i = 0; i < 8; ++i) {  // linear LDS dest, inverse-swizzled global source (G21)
    int idx = i * 256 + t;
    int r = idx >> 5, cs = idx & 31;
    gload16(qe + (size_t)(m0 + r) * 256 + ((cs ^ (r & 31)) * 8), &A[idx * 8]);
  }
  __syncthreads();

#pragma unroll
  for (int pi = 0; pi < 2; ++pi) {  // Z per (row, head): 512 pairs / 256 threads
    int p = pi * 256 + t;
    int r = p >> 3, hh = p & 7;
    float zs = 0.f;
#pragma unroll
    for (int c = 0; c < 4; ++c) {
      int cs = (hh * 4 + c) ^ (r & 31);
      f16x8 vv = *(const f16x8*)&A[r * 256 + cs * 8];
#pragma unroll
      for (int j = 0; j < 8; ++j) zs += (float)vv[j];
    }
    zbuf[r][hh] = 1.f / zs;
  }
  __syncthreads();

#pragma unroll
  for (int i = 0; i < 8; ++i) {  // rescale own staged slots: qs = e * rcpZ
    int idx = i * 256 + t;
    int r = idx >> 5, cs = idx & 31;
    int hh = (cs ^ (r & 31)) >> 2;
    float sc = zbuf[r][hh];
    f16x8 vv = *(const f16x8*)&A[idx * 8];
#pragma unroll
    for (int j = 0; j < 8; ++j) vv[j] = (fp16_t)((float)vv[j] * sc);
    *(f16x8*)&A[idx * 8] = vv;
  }
  __syncthreads();

  int n0 = w * 64;
  const fp16_t* Bp = Bpacky + (size_t)(m0 >> 12) * 65536 + (size_t)w * 16384;
  f32x4 acc[4][4];
#pragma unroll
  for (int mf = 0; mf < 4; ++mf)
#pragma unroll
    for (int nf = 0; nf < 4; ++nf) acc[mf][nf] = (f32x4){0.f, 0.f, 0.f, 0.f};
#pragma unroll
  for (int kk = 0; kk < 8; ++kk) {
    f16x8 af[4], bfr[4];
#pragma unroll
    for (int f = 0; f < 4; ++f) {
      int ra = f * 16 + lc;
      af[f] = *(const f16x8*)&A[ra * 256 + (((kk * 4 + lr) ^ (ra & 31)) * 8)];
      bfr[f] = *(const f16x8*)(Bp + (size_t)(kk * 4 + f) * 512 + l * 8);
    }
#pragma unroll
    for (int mf = 0; mf < 4; ++mf)
#pragma unroll
      for (int nf = 0; nf < 4; ++nf)
        acc[mf][nf] = __builtin_amdgcn_mfma_f32_16x16x32_f16(af[mf], bfr[nf], acc[mf][nf], 0, 0, 0);
  }
  float bv[4], gv[4];
#pragma unroll
  for (int nf = 0; nf < 4; ++nf) {
    int c = n0 + nf * 16 + lc;
    bv[nf] = b_out[c];
    gv[nf] = (gamma_out[c] + 1.f) * 16.f;
  }
#pragma unroll
  for (int mf = 0; mf < 4; ++mf)
#pragma unroll
    for (int r = 0; r < 4; ++r) {
      int row = m0 + mf * 16 + lr * 4 + r;
#pragma unroll
      for (int nf = 0; nf < 4; ++nf)
        y_out[(size_t)row * 256 + n0 + nf * 16 + lc] = (acc[mf][nf][r] + bv[nf]) * gv[nf];
    }
}

extern "C" void kernel_launch(void* const* d_in, const int* in_sizes, int n_in,
                              void* d_out, int out_size, void* d_ws, size_t ws_size,
                              hipStream_t stream) {
  const float* x        = (const float*)d_in[0];
  const float* gamma_in = (const float*)d_in[1];
  const float* w_qkv    = (const float*)d_in[2];
  const float* b_qkv    = (const float*)d_in[3];
  const float* mem_kv   = (const float*)d_in[4];
  const float* w_out    = (const float*)d_in[5];
  const float* b_out    = (const float*)d_in[6];
  const float* gamma_out= (const float*)d_in[7];
  float* y = (float*)d_out;

  char* ws = (char*)d_ws;
  fp16_t* qe     = (fp16_t*)(ws);                 // 32 MB    e = exp(q*scale-8), fp16
  fp16_t* Bpack  = (fp16_t*)(ws + 33554432);      // 384 KB   packed w_qkv frags
  fp16_t* Bpacky = (fp16_t*)(ws + 33947648);      // 2 MB     packed per-batch wt frags
  float*  part   = (float*)(ws + 36044800);       // 34.6 MB  S/Z partials (end ~71 MB)

  prep_pack<<<96, 256, 0, stream>>>(w_qkv, Bpack);
  gemm_qvk_ctx<<<1024, 256, 0, stream>>>(x, gamma_in, Bpack, b_qkv, qe, part);
  build_wt<<<128, 256, 0, stream>>>(part, w_out, mem_kv, Bpacky);
  gemm_y<<<1024, 256, 0, stream>>>(qe, Bpacky, b_out, gamma_out, y);
}